// Round 1
// baseline (756.079 us; speedup 1.0000x reference)
//
#include <hip/hip_runtime.h>
#include <math.h>

#define H 1024
#define S 4096
#define V 50257

// d_out layout: output[0..V) , hidden[V..V+H) , attn_weights[V+H..V+H+S)
#define OUT_HID  50257
#define OUT_ATTN 51281

// workspace layout (floats)
#define WS_GI   0      // 3072
#define WS_GH   3072   // 3072
#define WS_H    6144   // 1024
#define WS_V    7168   // 1024
#define WS_C0   8192   // 1 (padded)
#define WS_SC   8208   // 4096
#define WS_CTX  12304  // 1024

// K1: gi[k] = w_ih[k]·x + b_ih[k] (k<3H), gh[k] = w_hh[k]·h_prev + b_hh[k]
// one wave (64 lanes) per row; 6144 rows -> 1536 blocks x 256
__global__ __launch_bounds__(256) void k_gates(const int* __restrict__ word_input,
                                               const float* __restrict__ last_hidden,
                                               const float* __restrict__ emb,
                                               const float* __restrict__ w_ih,
                                               const float* __restrict__ w_hh,
                                               const float* __restrict__ b_ih,
                                               const float* __restrict__ b_hh,
                                               float* __restrict__ ws) {
    int wid  = (blockIdx.x * 256 + threadIdx.x) >> 6;   // 0..6143
    int lane = threadIdx.x & 63;
    const float* vec;
    const float* row;
    float bias;
    float* dst;
    if (wid < 3 * H) {
        int idx = word_input[0];
        vec  = emb + (size_t)idx * H;
        row  = w_ih + (size_t)wid * H;
        bias = b_ih[wid];
        dst  = ws + WS_GI + wid;
    } else {
        int k = wid - 3 * H;
        vec  = last_hidden;
        row  = w_hh + (size_t)k * H;
        bias = b_hh[k];
        dst  = ws + WS_GH + k;
    }
    float acc = 0.f;
    const float4* r4 = (const float4*)row;
    const float4* v4 = (const float4*)vec;
#pragma unroll
    for (int t = 0; t < 4; ++t) {
        int fi = t * 64 + lane;
        float4 a = r4[fi];
        float4 b = v4[fi];
        acc += a.x * b.x + a.y * b.y + a.z * b.z + a.w * b.w;
    }
    for (int off = 32; off > 0; off >>= 1) acc += __shfl_down(acc, off, 64);
    if (lane == 0) *dst = acc + bias;
}

// K2: GRU pointwise -> h ; writes ws[WS_H] and d_out hidden slot. 4 blocks x 256
__global__ __launch_bounds__(256) void k_gru(const float* __restrict__ last_hidden,
                                             float* __restrict__ ws,
                                             float* __restrict__ out) {
    int k = blockIdx.x * 256 + threadIdx.x;
    const float* gi = ws + WS_GI;
    const float* gh = ws + WS_GH;
    float r = 1.f / (1.f + expf(-(gi[k] + gh[k])));
    float z = 1.f / (1.f + expf(-(gi[H + k] + gh[H + k])));
    float n = tanhf(gi[2 * H + k] + r * gh[2 * H + k]);
    float h = (1.f - z) * n + z * last_hidden[k];
    ws[WS_H + k]     = h;
    out[OUT_HID + k] = h;
}

// K3: v[j] = sum_i attn_w[i][j]*h[i]  (blocks 0..3), c0 = attn_b·h (block 4)
__global__ __launch_bounds__(256) void k_v(const float* __restrict__ attn_w,
                                           const float* __restrict__ attn_b,
                                           float* __restrict__ ws) {
    const float* h = ws + WS_H;
    if (blockIdx.x < 4) {
        int j = blockIdx.x * 256 + threadIdx.x;
        float acc = 0.f;
#pragma unroll 8
        for (int i = 0; i < H; ++i) acc += attn_w[(size_t)i * H + j] * h[i];
        ws[WS_V + j] = acc;
    } else {
        __shared__ float red[256];
        float acc = 0.f;
        for (int i = threadIdx.x; i < H; i += 256) acc += attn_b[i] * h[i];
        red[threadIdx.x] = acc;
        __syncthreads();
        for (int s = 128; s > 0; s >>= 1) {
            if (threadIdx.x < s) red[threadIdx.x] += red[threadIdx.x + s];
            __syncthreads();
        }
        if (threadIdx.x == 0) ws[WS_C0] = red[0];
    }
}

// K4: scores[s] = enc[s]·v + c0 ; one wave per s, 1024 blocks x 256
__global__ __launch_bounds__(256) void k_scores(const float* __restrict__ enc,
                                                float* __restrict__ ws) {
    int s    = (blockIdx.x * 256 + threadIdx.x) >> 6;   // 0..4095
    int lane = threadIdx.x & 63;
    const float4* r4 = (const float4*)(enc + (size_t)s * H);
    const float4* v4 = (const float4*)(ws + WS_V);
    float acc = 0.f;
#pragma unroll
    for (int t = 0; t < 4; ++t) {
        int fi = t * 64 + lane;
        float4 a = r4[fi];
        float4 b = v4[fi];
        acc += a.x * b.x + a.y * b.y + a.z * b.z + a.w * b.w;
    }
    for (int off = 32; off > 0; off >>= 1) acc += __shfl_down(acc, off, 64);
    if (lane == 0) ws[WS_SC + s] = acc + ws[WS_C0];
}

// K5: softmax over 4096 scores, single block of 1024; writes attn weights to
// d_out and zeroes the context accumulator (ws is poisoned each launch).
__global__ __launch_bounds__(1024) void k_softmax(float* __restrict__ ws,
                                                  float* __restrict__ out) {
    __shared__ float red[1024];
    int tid = threadIdx.x;
    const float* sc = ws + WS_SC;
    float s0 = sc[tid], s1 = sc[tid + 1024], s2 = sc[tid + 2048], s3 = sc[tid + 3072];
    float m = fmaxf(fmaxf(s0, s1), fmaxf(s2, s3));
    red[tid] = m;
    __syncthreads();
    for (int s = 512; s > 0; s >>= 1) {
        if (tid < s) red[tid] = fmaxf(red[tid], red[tid + s]);
        __syncthreads();
    }
    m = red[0];
    __syncthreads();
    float e0 = expf(s0 - m), e1 = expf(s1 - m), e2 = expf(s2 - m), e3 = expf(s3 - m);
    red[tid] = e0 + e1 + e2 + e3;
    __syncthreads();
    for (int s = 512; s > 0; s >>= 1) {
        if (tid < s) red[tid] += red[tid + s];
        __syncthreads();
    }
    float inv = 1.f / red[0];
    float* aw = out + OUT_ATTN;
    aw[tid]        = e0 * inv;
    aw[tid + 1024] = e1 * inv;
    aw[tid + 2048] = e2 * inv;
    aw[tid + 3072] = e3 * inv;
    ws[WS_CTX + tid] = 0.f;   // zero context accumulator for K6
}

// K6: context[j] = sum_s w[s]*enc[s][j] ; 16 blocks x 1024, 256 rows/block,
// partial sums merged with atomicAdd.
__global__ __launch_bounds__(1024) void k_context(const float* __restrict__ enc,
                                                  const float* __restrict__ aw,
                                                  float* __restrict__ ws) {
    int j  = threadIdx.x;
    int s0 = blockIdx.x * 256;
    float acc = 0.f;
#pragma unroll 4
    for (int s = s0; s < s0 + 256; ++s) acc += aw[s] * enc[(size_t)s * H + j];
    atomicAdd(&ws[WS_CTX + j], acc);
}

// K7: output[v] = out_w[v,:]·[h;ctx] + out_b[v]. 4 waves/block, 1 row/wave,
// [h;ctx] (8 KB) staged in LDS. 12565 blocks x 256.
__global__ __launch_bounds__(256) void k_out(const float* __restrict__ out_w,
                                             const float* __restrict__ out_b,
                                             const float* __restrict__ ws,
                                             float* __restrict__ out) {
    __shared__ float4 sv[512];            // 2048 floats: h ++ context
    int tid = threadIdx.x;
    sv[tid]       = ((const float4*)(ws + WS_H))[tid];
    sv[256 + tid] = ((const float4*)(ws + WS_CTX))[tid];
    __syncthreads();
    int wave = tid >> 6, lane = tid & 63;
    int v = blockIdx.x * 4 + wave;
    if (v < V) {
        const float4* row = (const float4*)(out_w + (size_t)v * (2 * H));
        float acc = 0.f;
#pragma unroll
        for (int t = 0; t < 8; ++t) {
            int fi = t * 64 + lane;
            float4 a = row[fi];
            float4 b = sv[fi];
            acc += a.x * b.x + a.y * b.y + a.z * b.z + a.w * b.w;
        }
        for (int off = 32; off > 0; off >>= 1) acc += __shfl_down(acc, off, 64);
        if (lane == 0) out[v] = acc + out_b[v];
    }
}

extern "C" void kernel_launch(void* const* d_in, const int* in_sizes, int n_in,
                              void* d_out, int out_size, void* d_ws, size_t ws_size,
                              hipStream_t stream) {
    const int*   word_input  = (const int*)d_in[0];
    const float* last_hidden = (const float*)d_in[1];
    const float* enc         = (const float*)d_in[2];
    const float* emb         = (const float*)d_in[3];
    const float* w_ih        = (const float*)d_in[4];
    const float* w_hh        = (const float*)d_in[5];
    const float* b_ih        = (const float*)d_in[6];
    const float* b_hh        = (const float*)d_in[7];
    const float* attn_w      = (const float*)d_in[8];
    const float* attn_b      = (const float*)d_in[9];
    const float* out_w       = (const float*)d_in[10];
    const float* out_b       = (const float*)d_in[11];
    float* out = (float*)d_out;
    float* ws  = (float*)d_ws;

    k_gates  <<<1536, 256, 0, stream>>>(word_input, last_hidden, emb, w_ih, w_hh, b_ih, b_hh, ws);
    k_gru    <<<4,    256, 0, stream>>>(last_hidden, ws, out);
    k_v      <<<5,    256, 0, stream>>>(attn_w, attn_b, ws);
    k_scores <<<1024, 256, 0, stream>>>(enc, ws);
    k_softmax<<<1,   1024, 0, stream>>>(ws, out);
    k_context<<<16,  1024, 0, stream>>>(enc, out + OUT_ATTN, ws);
    k_out    <<<(V + 3) / 4, 256, 0, stream>>>(out_w, out_b, ws, out);
}

// Round 2
// 670.412 us; speedup vs baseline: 1.1278x; 1.1278x over previous
//
#include <hip/hip_runtime.h>
#include <math.h>

#define H 1024
#define S 4096
#define V 50257

// d_out layout: output[0..V) , hidden[V..V+H) , attn_weights[V+H..V+H+S)
#define OUT_HID  50257
#define OUT_ATTN 51281

// workspace layout (floats)
#define WS_GI   0      // 3072
#define WS_GH   3072   // 3072
#define WS_H    6144   // 1024
#define WS_V    7168   // 1024
#define WS_C0   8192   // 1 (padded)
#define WS_SC   8208   // 4096
#define WS_CTX  12304  // 1024

// K1: gi[k] = w_ih[k]·x + b_ih[k] (k<3H), gh[k] = w_hh[k]·h_prev + b_hh[k]
// one wave (64 lanes) per row; 6144 rows -> 1536 blocks x 256
__global__ __launch_bounds__(256) void k_gates(const int* __restrict__ word_input,
                                               const float* __restrict__ last_hidden,
                                               const float* __restrict__ emb,
                                               const float* __restrict__ w_ih,
                                               const float* __restrict__ w_hh,
                                               const float* __restrict__ b_ih,
                                               const float* __restrict__ b_hh,
                                               float* __restrict__ ws) {
    int wid  = (blockIdx.x * 256 + threadIdx.x) >> 6;   // 0..6143
    int lane = threadIdx.x & 63;
    const float* vec;
    const float* row;
    float bias;
    float* dst;
    if (wid < 3 * H) {
        int idx = word_input[0];
        vec  = emb + (size_t)idx * H;
        row  = w_ih + (size_t)wid * H;
        bias = b_ih[wid];
        dst  = ws + WS_GI + wid;
    } else {
        int k = wid - 3 * H;
        vec  = last_hidden;
        row  = w_hh + (size_t)k * H;
        bias = b_hh[k];
        dst  = ws + WS_GH + k;
    }
    float acc = 0.f;
    const float4* r4 = (const float4*)row;
    const float4* v4 = (const float4*)vec;
#pragma unroll
    for (int t = 0; t < 4; ++t) {
        int fi = t * 64 + lane;
        float4 a = r4[fi];
        float4 b = v4[fi];
        acc += a.x * b.x + a.y * b.y + a.z * b.z + a.w * b.w;
    }
    for (int off = 32; off > 0; off >>= 1) acc += __shfl_down(acc, off, 64);
    if (lane == 0) *dst = acc + bias;
}

// K2: GRU pointwise -> h ; also zero-inits WS_V / WS_C0 for K3's atomics.
// 4 blocks x 256.
__global__ __launch_bounds__(256) void k_gru(const float* __restrict__ last_hidden,
                                             float* __restrict__ ws,
                                             float* __restrict__ out) {
    int k = blockIdx.x * 256 + threadIdx.x;
    const float* gi = ws + WS_GI;
    const float* gh = ws + WS_GH;
    float r = 1.f / (1.f + expf(-(gi[k] + gh[k])));
    float z = 1.f / (1.f + expf(-(gi[H + k] + gh[H + k])));
    float n = tanhf(gi[2 * H + k] + r * gh[2 * H + k]);
    float h = (1.f - z) * n + z * last_hidden[k];
    ws[WS_H + k]     = h;
    out[OUT_HID + k] = h;
    ws[WS_V + k]     = 0.f;       // for K3 atomics
    if (k == 0) ws[WS_C0] = 0.f;
}

// K3: v[j] = sum_i attn_w[i][j]*h[i]  split-K over 8 i-chunks (blocks 0..31,
// atomicAdd), c0 = attn_b·h (block 32).
__global__ __launch_bounds__(256) void k_v(const float* __restrict__ attn_w,
                                           const float* __restrict__ attn_b,
                                           float* __restrict__ ws) {
    const float* h = ws + WS_H;
    if (blockIdx.x < 32) {
        int jb = blockIdx.x & 3;
        int ib = blockIdx.x >> 2;          // 0..7
        int j  = jb * 256 + threadIdx.x;
        int i0 = ib * 128;
        float acc = 0.f;
#pragma unroll 8
        for (int i = i0; i < i0 + 128; ++i) acc += attn_w[(size_t)i * H + j] * h[i];
        atomicAdd(&ws[WS_V + j], acc);
    } else {
        __shared__ float red[256];
        float acc = 0.f;
        for (int i = threadIdx.x; i < H; i += 256) acc += attn_b[i] * h[i];
        red[threadIdx.x] = acc;
        __syncthreads();
        for (int s = 128; s > 0; s >>= 1) {
            if (threadIdx.x < s) red[threadIdx.x] += red[threadIdx.x + s];
            __syncthreads();
        }
        if (threadIdx.x == 0) atomicAdd(&ws[WS_C0], red[0]);
    }
}

// K4: scores[s] = enc[s]·v + c0 ; one wave per s, 1024 blocks x 256
__global__ __launch_bounds__(256) void k_scores(const float* __restrict__ enc,
                                                float* __restrict__ ws) {
    int s    = (blockIdx.x * 256 + threadIdx.x) >> 6;   // 0..4095
    int lane = threadIdx.x & 63;
    const float4* r4 = (const float4*)(enc + (size_t)s * H);
    const float4* v4 = (const float4*)(ws + WS_V);
    float acc = 0.f;
#pragma unroll
    for (int t = 0; t < 4; ++t) {
        int fi = t * 64 + lane;
        float4 a = r4[fi];
        float4 b = v4[fi];
        acc += a.x * b.x + a.y * b.y + a.z * b.z + a.w * b.w;
    }
    for (int off = 32; off > 0; off >>= 1) acc += __shfl_down(acc, off, 64);
    if (lane == 0) ws[WS_SC + s] = acc + ws[WS_C0];
}

// K5: softmax over 4096 scores, single block of 1024; writes attn weights to
// d_out and zeroes the context accumulator (ws is poisoned each launch).
__global__ __launch_bounds__(1024) void k_softmax(float* __restrict__ ws,
                                                  float* __restrict__ out) {
    __shared__ float red[1024];
    int tid = threadIdx.x;
    const float* sc = ws + WS_SC;
    float s0 = sc[tid], s1 = sc[tid + 1024], s2 = sc[tid + 2048], s3 = sc[tid + 3072];
    float m = fmaxf(fmaxf(s0, s1), fmaxf(s2, s3));
    red[tid] = m;
    __syncthreads();
    for (int s = 512; s > 0; s >>= 1) {
        if (tid < s) red[tid] = fmaxf(red[tid], red[tid + s]);
        __syncthreads();
    }
    m = red[0];
    __syncthreads();
    float e0 = expf(s0 - m), e1 = expf(s1 - m), e2 = expf(s2 - m), e3 = expf(s3 - m);
    red[tid] = e0 + e1 + e2 + e3;
    __syncthreads();
    for (int s = 512; s > 0; s >>= 1) {
        if (tid < s) red[tid] += red[tid + s];
        __syncthreads();
    }
    float inv = 1.f / red[0];
    float* aw = out + OUT_ATTN;
    aw[tid]        = e0 * inv;
    aw[tid + 1024] = e1 * inv;
    aw[tid + 2048] = e2 * inv;
    aw[tid + 3072] = e3 * inv;
    ws[WS_CTX + tid] = 0.f;   // zero context accumulator for K6
}

// K6: context[j] = sum_s w[s]*enc[s][j] ; 64 blocks x 1024, 64 rows/block,
// partial sums merged with atomicAdd.
__global__ __launch_bounds__(1024) void k_context(const float* __restrict__ enc,
                                                  const float* __restrict__ aw,
                                                  float* __restrict__ ws) {
    int j  = threadIdx.x;
    int s0 = blockIdx.x * 64;
    float acc = 0.f;
#pragma unroll 4
    for (int s = s0; s < s0 + 64; ++s) acc += aw[s] * enc[(size_t)s * H + j];
    atomicAdd(&ws[WS_CTX + j], acc);
}

// K7: output[v] = out_w[v,:]·[h;ctx] + out_b[v]. 4 waves/block, 2 rows/wave
// (two independent acc chains for load pipelining), [h;ctx] staged in LDS.
__global__ __launch_bounds__(256) void k_out(const float* __restrict__ out_w,
                                             const float* __restrict__ out_b,
                                             const float* __restrict__ ws,
                                             float* __restrict__ out) {
    __shared__ float4 sv[512];            // 2048 floats: h ++ context
    int tid = threadIdx.x;
    sv[tid]       = ((const float4*)(ws + WS_H))[tid];
    sv[256 + tid] = ((const float4*)(ws + WS_CTX))[tid];
    __syncthreads();
    int wave = tid >> 6, lane = tid & 63;
    int v0 = blockIdx.x * 8 + wave * 2;
    if (v0 >= V) return;
    const float4* r0 = (const float4*)(out_w + (size_t)v0 * (2 * H));
    const float4* r1 = (const float4*)(out_w + (size_t)(v0 + 1) * (2 * H));
    bool has1 = (v0 + 1) < V;
    float acc0 = 0.f, acc1 = 0.f;
#pragma unroll
    for (int t = 0; t < 8; ++t) {
        int fi = t * 64 + lane;
        float4 b = sv[fi];
        float4 a0 = r0[fi];
        acc0 += a0.x * b.x + a0.y * b.y + a0.z * b.z + a0.w * b.w;
        if (has1) {
            float4 a1 = r1[fi];
            acc1 += a1.x * b.x + a1.y * b.y + a1.z * b.z + a1.w * b.w;
        }
    }
    for (int off = 32; off > 0; off >>= 1) {
        acc0 += __shfl_down(acc0, off, 64);
        acc1 += __shfl_down(acc1, off, 64);
    }
    if (lane == 0) {
        out[v0] = acc0 + out_b[v0];
        if (has1) out[v0 + 1] = acc1 + out_b[v0 + 1];
    }
}

extern "C" void kernel_launch(void* const* d_in, const int* in_sizes, int n_in,
                              void* d_out, int out_size, void* d_ws, size_t ws_size,
                              hipStream_t stream) {
    const int*   word_input  = (const int*)d_in[0];
    const float* last_hidden = (const float*)d_in[1];
    const float* enc         = (const float*)d_in[2];
    const float* emb         = (const float*)d_in[3];
    const float* w_ih        = (const float*)d_in[4];
    const float* w_hh        = (const float*)d_in[5];
    const float* b_ih        = (const float*)d_in[6];
    const float* b_hh        = (const float*)d_in[7];
    const float* attn_w      = (const float*)d_in[8];
    const float* attn_b      = (const float*)d_in[9];
    const float* out_w       = (const float*)d_in[10];
    const float* out_b       = (const float*)d_in[11];
    float* out = (float*)d_out;
    float* ws  = (float*)d_ws;

    k_gates  <<<1536, 256, 0, stream>>>(word_input, last_hidden, emb, w_ih, w_hh, b_ih, b_hh, ws);
    k_gru    <<<4,    256, 0, stream>>>(last_hidden, ws, out);
    k_v      <<<33,   256, 0, stream>>>(attn_w, attn_b, ws);
    k_scores <<<1024, 256, 0, stream>>>(enc, ws);
    k_softmax<<<1,   1024, 0, stream>>>(ws, out);
    k_context<<<64,  1024, 0, stream>>>(enc, out + OUT_ATTN, ws);
    k_out    <<<(V + 7) / 8, 256, 0, stream>>>(out_w, out_b, ws, out);
}